// Round 11
// baseline (196.443 us; speedup 1.0000x reference)
//
#include <hip/hip_runtime.h>

#define NN 3072
#define FF 512
#define HH 8
#define DD 64
#define SLOPEV 0.2f
#define CH2 64
#define NC2 (NN/CH2)   // 48

typedef __bf16  bf16x8 __attribute__((ext_vector_type(8)));
typedef __bf16  bf16x4 __attribute__((ext_vector_type(4)));
typedef short   s16x8  __attribute__((ext_vector_type(8)));
typedef float   f32x4  __attribute__((ext_vector_type(4)));
typedef unsigned long long u64;

#define MFMA16(a,b,c) __builtin_amdgcn_mfma_f32_16x16x32_bf16((a),(b),(c),0,0,0)

__device__ __forceinline__ short f2bf(float x){ __bf16 b=(__bf16)x; return __builtin_bit_cast(short,b); }
__device__ __forceinline__ float bf2f(short s){ return (float)__builtin_bit_cast(__bf16,s); }
__device__ __forceinline__ bf16x8 ldbf8(const short* p){ return __builtin_bit_cast(bf16x8, *(const s16x8*)p); }

__device__ __forceinline__ void gload16(const void* g, void* l){
  __builtin_amdgcn_global_load_lds(
      (const __attribute__((address_space(1))) void*)(uintptr_t)g,
      (__attribute__((address_space(3))) void*)(uint32_t)(uintptr_t)l, 16, 0, 0);
}

// ---- K0a: split h (fp32) into bf16 hi/lo ----
__global__ __launch_bounds__(256) void k_split_h(const float* __restrict__ h,
    short* __restrict__ hhi, short* __restrict__ hlo){
  size_t base = ((size_t)blockIdx.x*256 + threadIdx.x)*8;
  float4 v0 = *(const float4*)(h+base);
  float4 v1 = *(const float4*)(h+base+4);
  float vv[8] = {v0.x,v0.y,v0.z,v0.w,v1.x,v1.y,v1.z,v1.w};
  s16x8 hi, lo;
  #pragma unroll
  for (int j=0;j<8;j++){ short s=f2bf(vv[j]); hi[j]=s; lo[j]=f2bf(vv[j]-bf2f(s)); }
  *(s16x8*)(hhi+base)=hi; *(s16x8*)(hlo+base)=lo;
}

// ---- K0b: W[h][f][d] -> WT[h][d][f] bf16 hi/lo, plus wa = W @ a (fp32) ----
__global__ __launch_bounds__(64) void k_wt(const float* __restrict__ W, const float* __restrict__ a,
    short* __restrict__ wthi, short* __restrict__ wtlo,
    float* __restrict__ wasrc, float* __restrict__ wadst){
  int h = blockIdx.y, f0 = blockIdx.x*8, d = threadIdx.x;
  float asv = a[h*2*DD + d];
  float adv = a[h*2*DD + DD + d];
  s16x8 vh, vl;
  #pragma unroll
  for (int j=0;j<8;j++){
    float v = W[((size_t)h*FF + f0 + j)*DD + d];
    short s = f2bf(v); vh[j]=s; vl[j]=f2bf(v-bf2f(s));
    float ws_ = v*asv, wd_ = v*adv;
    #pragma unroll
    for (int m=1;m<64;m<<=1){ ws_ += __shfl_xor(ws_,m,64); wd_ += __shfl_xor(wd_,m,64); }
    if (d==0){ wasrc[h*FF+f0+j]=ws_; wadst[h*FF+f0+j]=wd_; }
  }
  size_t o = ((size_t)h*DD + d)*FF + f0;
  *(s16x8*)(wthi+o)=vh; *(s16x8*)(wtlo+o)=vl;
}

// ---- K0c: bit-pack adj via ballot (grid-stride) ----
__global__ __launch_bounds__(256) void k_pack(const int* __restrict__ adj, u64* __restrict__ padj){
  const int total = NN*NN;
  for (int idx = blockIdx.x*256 + threadIdx.x; idx < total; idx += gridDim.x*256){
    u64 b = __ballot(adj[idx] > 0);
    if ((threadIdx.x & 63) == 0) padj[idx>>6] = b;
  }
}

// ---- K1: src/dst for ALL heads, h read once per row ----
__global__ __launch_bounds__(256) void k_srcdst(const float* __restrict__ h,
    const float* __restrict__ wasrc, const float* __restrict__ wadst,
    float* __restrict__ src, float* __restrict__ dst){
  int n = blockIdx.x*4 + (threadIdx.x>>6);
  int lane = threadIdx.x & 63;
  const float* hp = h + (size_t)n*FF + lane*8;
  float4 x0 = *(const float4*)hp, x1 = *(const float4*)(hp+4);
  float xs[8] = {x0.x,x0.y,x0.z,x0.w,x1.x,x1.y,x1.z,x1.w};
  float ps[HH], pd[HH];
  #pragma unroll
  for (int hh=0; hh<HH; hh++){
    const float* sp = wasrc + (size_t)hh*FF + lane*8;
    const float* dp = wadst + (size_t)hh*FF + lane*8;
    float4 s0 = *(const float4*)sp, s1 = *(const float4*)(sp+4);
    float4 t0 = *(const float4*)dp, t1 = *(const float4*)(dp+4);
    ps[hh] = xs[0]*s0.x + xs[1]*s0.y + xs[2]*s0.z + xs[3]*s0.w
           + xs[4]*s1.x + xs[5]*s1.y + xs[6]*s1.z + xs[7]*s1.w;
    pd[hh] = xs[0]*t0.x + xs[1]*t0.y + xs[2]*t0.z + xs[3]*t0.w
           + xs[4]*t1.x + xs[5]*t1.y + xs[6]*t1.z + xs[7]*t1.w;
  }
  #pragma unroll
  for (int m=1;m<64;m<<=1){
    #pragma unroll
    for (int hh=0; hh<HH; hh++){ ps[hh] += __shfl_xor(ps[hh],m,64); pd[hh] += __shfl_xor(pd[hh],m,64); }
  }
  if (lane==0){
    #pragma unroll
    for (int hh=0; hh<HH; hh++){ src[hh*NN+n]=ps[hh]; dst[hh*NN+n]=pd[hh]; }
  }
}

// ---- K1b: rowsums[h][n] ----
__global__ __launch_bounds__(256) void k_rowsum(const u64* __restrict__ padj,
    const float* __restrict__ src, const float* __restrict__ dst,
    float* __restrict__ rowsums){
  int wid = blockIdx.x*4 + (threadIdx.x>>6);
  int lane = threadIdx.x & 63;
  int h = wid / NN, n = wid - h*NN;
  float srcv = src[h*NN + n];
  const float* dsth = dst + h*NN;
  const u64* arow = padj + (size_t)n*(NN/64);
  float s = 0.f;
  #pragma unroll 4
  for (int i=0;i<NN/64;i++){
    u64 w = arow[i];
    float dv = dsth[i*64 + lane];
    float ev = srcv + dv;
    ev = fmaxf(ev, SLOPEV*ev);
    s += ((w >> lane) & 1ull) ? __expf(ev) : 0.f;
  }
  #pragma unroll
  for (int m=1;m<64;m<<=1) s += __shfl_xor(s, m, 64);
  if (lane == 0) rowsums[h*NN + n] = s;
}

// ---- K2: ht = h @ W[h] (3-term split, fp32-accurate); store bf16 htT[h][d][n] ----
__global__ __launch_bounds__(128) void k_ht(const short* __restrict__ hhi, const short* __restrict__ hlo,
    const short* __restrict__ wthi, const short* __restrict__ wtlo,
    short* __restrict__ hthi){
  __shared__ short tH[64][40];
  int h = blockIdx.y, n0 = blockIdx.x*32;
  int w = threadIdx.x>>6, lane = threadIdx.x&63;
  int r15 = lane&15, g = lane>>4;
  int arow = n0 + w*16 + r15;
  f32x4 acc[4] = {{0.f,0.f,0.f,0.f},{0.f,0.f,0.f,0.f},{0.f,0.f,0.f,0.f},{0.f,0.f,0.f,0.f}};
  const short* ha = hhi + (size_t)arow*FF + g*8;
  const short* la = hlo + (size_t)arow*FF + g*8;
  for (int kk=0; kk<FF; kk+=32){
    bf16x8 ahi = ldbf8(ha+kk), alo = ldbf8(la+kk);
    #pragma unroll
    for (int c=0;c<4;c++){
      size_t bo = ((size_t)h*DD + c*16 + r15)*FF + g*8 + kk;
      bf16x8 bh = ldbf8(wthi + bo), bl = ldbf8(wtlo + bo);
      acc[c] = MFMA16(ahi,bh,acc[c]);
      acc[c] = MFMA16(ahi,bl,acc[c]);
      acc[c] = MFMA16(alo,bh,acc[c]);
    }
  }
  #pragma unroll
  for (int c=0;c<4;c++){
    #pragma unroll
    for (int r=0;r<4;r++){
      int dloc = c*16 + r15, nloc = w*16 + g*4 + r;
      tH[dloc][nloc] = f2bf(acc[c][r]);
    }
  }
  __syncthreads();
  int row = threadIdx.x>>1, half = threadIdx.x&1;
  size_t o = ((size_t)h*DD + row)*NN + n0 + half*16;
  *(s16x8*)(hthi + o)     = *(const s16x8*)&tH[row][half*16];
  *(s16x8*)(hthi + o + 8) = *(const s16x8*)&tH[row][half*16+8];
}

// ---- K3a: k_pv — staged htT + recomputed p + MFMA; NO att stores ----
__global__ __launch_bounds__(512, 8) void k_pv(const u64* __restrict__ padj,
    const float* __restrict__ src, const float* __restrict__ dst,
    const float* __restrict__ rowsums,
    const short* __restrict__ hthi, float* __restrict__ dout){
  __shared__ short hA[64][CH2], hB[64][CH2];
  __shared__ short pA[32][CH2], pB[32][CH2];
  int bid = blockIdx.x;
  int h = bid & 7, n0 = (bid >> 3) * 32;
  int t = threadIdx.x;
  int r = t>>4, j = t&15;
  int nrow = n0 + r;
  float srcv = src[h*NN + nrow];
  const float* dsth = dst + h*NN;
  const u64* arow = padj + (size_t)nrow*(NN/64);

  int wv = t>>6, lane = t&63, r15 = lane&15, g = lane>>4;
  int cblk = wv&3, nh = wv>>2;
  int drow = t>>3;
  int sslot = (t&7) ^ (drow&7);
  const short* gh = hthi + ((size_t)(h*DD) + drow)*NN + sslot*8;

  gload16(gh, &hA[wv*8][0]);

  float tot = rowsums[h*NN + nrow];
  float inv = (tot > 0.f) ? 1.f/tot : (1.f/(float)NN);
  bool am = !(tot > 0.f);

  f32x4 acc = {0.f,0.f,0.f,0.f};
  int aoff0 = (cblk*16 + r15)*(CH2*2);
  int boff0 = (nh*16 + r15)*(CH2*2);
  int csw   = (r15&7)<<4;
  int pofs  = r*(CH2*2) + ((j*8) ^ ((r&7)<<4));

  u64 bits = arow[0];
  const float* dvp = dsth + j*4;
  float4 dv = *(const float4*)dvp;

  #pragma unroll 2
  for (int c=0;c<NC2-1;c++){
    short (*hc)[CH2] = (c&1)?hB:hA;
    short (*hn)[CH2] = (c&1)?hA:hB;
    short (*pc)[CH2] = (c&1)?pB:pA;

    gload16(gh + (c+1)*CH2, &hn[wv*8][0]);
    u64 bits_n = arow[c+1];
    float4 dv_n = *(const float4*)(dvp + (c+1)*CH2);

    float o[4];
    #pragma unroll
    for (int e=0;e<4;e++){
      float ev = srcv + ((const float*)&dv)[e];
      ev = fmaxf(ev, SLOPEV*ev);
      float p = ((bits >> (j*4 + e)) & 1ull) ? __expf(ev) : 0.f;
      if (am) p = 1.f;
      o[e] = p * inv;
    }
    bf16x4 pb;
    #pragma unroll
    for (int e=0;e<4;e++) pb[e] = (__bf16)o[e];
    *(bf16x4*)((char*)pc + pofs) = pb;

    __builtin_amdgcn_sched_barrier(0);
    asm volatile("s_waitcnt vmcnt(5) lgkmcnt(0)" ::: "memory");
    __builtin_amdgcn_sched_barrier(0);
    __builtin_amdgcn_s_barrier();
    __builtin_amdgcn_sched_barrier(0);

    const char* hcB = (const char*)hc;
    const char* pcB = (const char*)pc;
    #pragma unroll
    for (int ks=0;ks<2;ks++){
      int kb = (g*16 + ks*64) ^ csw;
      bf16x8 bf = *(const bf16x8*)(pcB + boff0 + kb);
      bf16x8 ah = *(const bf16x8*)(hcB + aoff0 + kb);
      acc = MFMA16(ah, bf, acc);
    }
    asm volatile("" ::: "memory");
    __builtin_amdgcn_s_barrier();
    __builtin_amdgcn_sched_barrier(0);

    bits = bits_n; dv = dv_n;
  }

  { // peeled last chunk
    const int c = NC2-1;
    short (*hc)[CH2] = (c&1)?hB:hA;
    short (*pc)[CH2] = (c&1)?pB:pA;
    float o[4];
    #pragma unroll
    for (int e=0;e<4;e++){
      float ev = srcv + ((const float*)&dv)[e];
      ev = fmaxf(ev, SLOPEV*ev);
      float p = ((bits >> (j*4 + e)) & 1ull) ? __expf(ev) : 0.f;
      if (am) p = 1.f;
      o[e] = p * inv;
    }
    bf16x4 pb;
    #pragma unroll
    for (int e=0;e<4;e++) pb[e] = (__bf16)o[e];
    *(bf16x4*)((char*)pc + pofs) = pb;

    __builtin_amdgcn_sched_barrier(0);
    asm volatile("s_waitcnt vmcnt(0) lgkmcnt(0)" ::: "memory");
    __builtin_amdgcn_sched_barrier(0);
    __builtin_amdgcn_s_barrier();
    __builtin_amdgcn_sched_barrier(0);

    const char* hcB = (const char*)hc;
    const char* pcB = (const char*)pc;
    #pragma unroll
    for (int ks=0;ks<2;ks++){
      int kb = (g*16 + ks*64) ^ csw;
      bf16x8 bf = *(const bf16x8*)(pcB + boff0 + kb);
      bf16x8 ah = *(const bf16x8*)(hcB + aoff0 + kb);
      acc = MFMA16(ah, bf, acc);
    }
  }

  int n = n0 + nh*16 + r15;
  size_t ob = (size_t)n*(HH*DD) + h*DD + cblk*16 + g*4;
  *(f32x4*)(dout+ob) = acc;
}

// ---- K3b: k_att_write — pure streaming att writer (fill-kernel pattern) ----
// wave owns 4 whole rows (48KB contiguous); each store instr = 1KB contiguous;
// block covers 384KB contiguous. Plain cached stores (fill kernel proves 6.9 TB/s).
__global__ __launch_bounds__(512) void k_att_write(const u64* __restrict__ padj,
    const float* __restrict__ src, const float* __restrict__ dst,
    const float* __restrict__ rowsums, float* __restrict__ dout){
  const size_t OUTOFF = (size_t)NN*HH*DD;
  int wv = threadIdx.x>>6, lane = threadIdx.x&63;
  int base_row = (blockIdx.x*8 + wv)*4;
  int widx = lane>>4, sh = (lane&15)*4;
  #pragma unroll
  for (int k=0;k<4;k++){
    int row = base_row + k;                       // flat h*NN+n
    int h = row / NN;
    int n = row - h*NN;
    float srcv = src[row];
    float tot = rowsums[row];
    float inv = (tot > 0.f) ? 1.f/tot : (1.f/(float)NN);
    bool am = !(tot > 0.f);
    const float* dsth = dst + h*NN;
    const u64* arow = padj + (size_t)n*(NN/64);
    float* attrow = dout + OUTOFF + (size_t)row*NN;
    #pragma unroll 4
    for (int i=0;i<NN/256;i++){
      u64 w = arow[i*4 + widx];
      const float* dp = dsth + i*256 + lane*4;
      float4 dv = *(const float4*)dp;
      float dj[4] = {dv.x, dv.y, dv.z, dv.w};
      f32x4 o;
      #pragma unroll
      for (int e=0;e<4;e++){
        float ev = srcv + dj[e];
        ev = fmaxf(ev, SLOPEV*ev);
        float p = ((w >> (sh+e)) & 1ull) ? __expf(ev) : 0.f;
        if (am) p = 1.f;
        o[e] = p * inv;
      }
      *(f32x4*)(attrow + i*256 + lane*4) = o;
    }
  }
}

extern "C" void kernel_launch(void* const* d_in, const int* in_sizes, int n_in,
                              void* d_out, int out_size, void* d_ws, size_t ws_size,
                              hipStream_t stream) {
  const float* h   = (const float*)d_in[0];
  const int*   adj = (const int*)d_in[1];
  const float* W   = (const float*)d_in[2];
  const float* a   = (const float*)d_in[3];
  float* out = (float*)d_out;

  short* hhi  = (short*)d_ws;
  short* hlo  = hhi  + (size_t)NN*FF;
  short* wthi = hlo  + (size_t)NN*FF;
  short* wtlo = wthi + (size_t)HH*DD*FF;
  short* hthi = wtlo + (size_t)HH*DD*FF;
  float* wasrc= (float*)(hthi + (size_t)HH*DD*NN);
  float* wadst= wasrc + HH*FF;
  float* srcb = wadst + HH*FF;
  float* dstb = srcb + HH*NN;
  float* rsum = dstb + HH*NN;
  u64*   padj = (u64*)(rsum + HH*NN);

  k_split_h  <<<dim3(NN*FF/(256*8)), 256, 0, stream>>>(h, hhi, hlo);
  k_wt       <<<dim3(FF/8, HH), 64, 0, stream>>>(W, a, wthi, wtlo, wasrc, wadst);
  k_pack     <<<dim3(2048), 256, 0, stream>>>(adj, padj);
  k_srcdst   <<<dim3(NN/4), 256, 0, stream>>>(h, wasrc, wadst, srcb, dstb);
  k_ht       <<<dim3(NN/32, HH), 128, 0, stream>>>(hhi, hlo, wthi, wtlo, hthi);
  k_rowsum   <<<dim3(HH*NN/4), 256, 0, stream>>>(padj, srcb, dstb, rsum);
  k_pv       <<<dim3(NN/32*HH), 512, 0, stream>>>(padj, srcb, dstb, rsum, hthi, out);
  k_att_write<<<dim3(HH*NN/32), 512, 0, stream>>>(padj, srcb, dstb, rsum, out);
}

// Round 12
// 153.503 us; speedup vs baseline: 1.2797x; 1.2797x over previous
//
#include <hip/hip_runtime.h>

#define NN 3072
#define FF 512
#define HH 8
#define DD 64
#define SLOPEV 0.2f
#define CH2 64
#define NC2 (NN/CH2)   // 48

typedef __bf16  bf16x8 __attribute__((ext_vector_type(8)));
typedef __bf16  bf16x4 __attribute__((ext_vector_type(4)));
typedef short   s16x8  __attribute__((ext_vector_type(8)));
typedef float   f32x4  __attribute__((ext_vector_type(4)));
typedef unsigned long long u64;

#define MFMA16(a,b,c) __builtin_amdgcn_mfma_f32_16x16x32_bf16((a),(b),(c),0,0,0)

__device__ __forceinline__ short f2bf(float x){ __bf16 b=(__bf16)x; return __builtin_bit_cast(short,b); }
__device__ __forceinline__ float bf2f(short s){ return (float)__builtin_bit_cast(__bf16,s); }
__device__ __forceinline__ bf16x8 ldbf8(const short* p){ return __builtin_bit_cast(bf16x8, *(const s16x8*)p); }

__device__ __forceinline__ void gload16(const void* g, void* l){
  __builtin_amdgcn_global_load_lds(
      (const __attribute__((address_space(1))) void*)(uintptr_t)g,
      (__attribute__((address_space(3))) void*)(uint32_t)(uintptr_t)l, 16, 0, 0);
}

// ---- K0: W[h][f][d] -> WT[h][d][f] bf16 hi/lo, plus wa = W @ a (fp32) ----
__global__ __launch_bounds__(64) void k_wt(const float* __restrict__ W, const float* __restrict__ a,
    short* __restrict__ wthi, short* __restrict__ wtlo,
    float* __restrict__ wasrc, float* __restrict__ wadst){
  int h = blockIdx.y, f0 = blockIdx.x*8, d = threadIdx.x;
  float asv = a[h*2*DD + d];
  float adv = a[h*2*DD + DD + d];
  s16x8 vh, vl;
  #pragma unroll
  for (int j=0;j<8;j++){
    float v = W[((size_t)h*FF + f0 + j)*DD + d];
    short s = f2bf(v); vh[j]=s; vl[j]=f2bf(v-bf2f(s));
    float ws_ = v*asv, wd_ = v*adv;
    #pragma unroll
    for (int m=1;m<64;m<<=1){ ws_ += __shfl_xor(ws_,m,64); wd_ += __shfl_xor(wd_,m,64); }
    if (d==0){ wasrc[h*FF+f0+j]=ws_; wadst[h*FF+f0+j]=wd_; }
  }
  size_t o = ((size_t)h*DD + d)*FF + f0;
  *(s16x8*)(wthi+o)=vh; *(s16x8*)(wtlo+o)=vl;
}

// ---- K0c: bit-pack adj via ballot (grid-stride) ----
__global__ __launch_bounds__(256) void k_pack(const int* __restrict__ adj, u64* __restrict__ padj){
  const int total = NN*NN;
  for (int idx = blockIdx.x*256 + threadIdx.x; idx < total; idx += gridDim.x*256){
    u64 b = __ballot(adj[idx] > 0);
    if ((threadIdx.x & 63) == 0) padj[idx>>6] = b;
  }
}

// ---- K1: src/dst for ALL heads, h read once per row ----
__global__ __launch_bounds__(256) void k_srcdst(const float* __restrict__ h,
    const float* __restrict__ wasrc, const float* __restrict__ wadst,
    float* __restrict__ src, float* __restrict__ dst){
  int n = blockIdx.x*4 + (threadIdx.x>>6);
  int lane = threadIdx.x & 63;
  const float* hp = h + (size_t)n*FF + lane*8;
  float4 x0 = *(const float4*)hp, x1 = *(const float4*)(hp+4);
  float xs[8] = {x0.x,x0.y,x0.z,x0.w,x1.x,x1.y,x1.z,x1.w};
  float ps[HH], pd[HH];
  #pragma unroll
  for (int hh=0; hh<HH; hh++){
    const float* sp = wasrc + (size_t)hh*FF + lane*8;
    const float* dp = wadst + (size_t)hh*FF + lane*8;
    float4 s0 = *(const float4*)sp, s1 = *(const float4*)(sp+4);
    float4 t0 = *(const float4*)dp, t1 = *(const float4*)(dp+4);
    ps[hh] = xs[0]*s0.x + xs[1]*s0.y + xs[2]*s0.z + xs[3]*s0.w
           + xs[4]*s1.x + xs[5]*s1.y + xs[6]*s1.z + xs[7]*s1.w;
    pd[hh] = xs[0]*t0.x + xs[1]*t0.y + xs[2]*t0.z + xs[3]*t0.w
           + xs[4]*t1.x + xs[5]*t1.y + xs[6]*t1.z + xs[7]*t1.w;
  }
  #pragma unroll
  for (int m=1;m<64;m<<=1){
    #pragma unroll
    for (int hh=0; hh<HH; hh++){ ps[hh] += __shfl_xor(ps[hh],m,64); pd[hh] += __shfl_xor(pd[hh],m,64); }
  }
  if (lane==0){
    #pragma unroll
    for (int hh=0; hh<HH; hh++){ src[hh*NN+n]=ps[hh]; dst[hh*NN+n]=pd[hh]; }
  }
}

// ---- K2: ht = h @ W[h]; h read fp32 + split in-register (3-term MFMA, fp32-accurate);
//          LDS-transpose epilogue -> coalesced bf16 htT[h][d][n] stores ----
__global__ __launch_bounds__(128) void k_ht(const float* __restrict__ h,
    const short* __restrict__ wthi, const short* __restrict__ wtlo,
    short* __restrict__ hthi){
  __shared__ short tH[64][40];
  int hh = blockIdx.y, n0 = blockIdx.x*32;
  int w = threadIdx.x>>6, lane = threadIdx.x&63;
  int r15 = lane&15, g = lane>>4;
  int arow = n0 + w*16 + r15;
  f32x4 acc[4] = {{0.f,0.f,0.f,0.f},{0.f,0.f,0.f,0.f},{0.f,0.f,0.f,0.f},{0.f,0.f,0.f,0.f}};
  const float* ha = h + (size_t)arow*FF + g*8;
  for (int kk=0; kk<FF; kk+=32){
    float4 x0 = *(const float4*)(ha+kk), x1 = *(const float4*)(ha+kk+4);
    float xv[8] = {x0.x,x0.y,x0.z,x0.w,x1.x,x1.y,x1.z,x1.w};
    bf16x8 ahi, alo;
    #pragma unroll
    for (int e=0;e<8;e++){
      short s = f2bf(xv[e]);
      ahi[e] = __builtin_bit_cast(__bf16, s);
      alo[e] = (__bf16)(xv[e] - bf2f(s));
    }
    #pragma unroll
    for (int c=0;c<4;c++){
      size_t bo = ((size_t)hh*DD + c*16 + r15)*FF + g*8 + kk;
      bf16x8 bh = ldbf8(wthi + bo), bl = ldbf8(wtlo + bo);
      acc[c] = MFMA16(ahi,bh,acc[c]);
      acc[c] = MFMA16(ahi,bl,acc[c]);
      acc[c] = MFMA16(alo,bh,acc[c]);
    }
  }
  #pragma unroll
  for (int c=0;c<4;c++){
    #pragma unroll
    for (int r=0;r<4;r++){
      int dloc = c*16 + r15, nloc = w*16 + g*4 + r;
      tH[dloc][nloc] = f2bf(acc[c][r]);
    }
  }
  __syncthreads();
  int row = threadIdx.x>>1, half = threadIdx.x&1;
  size_t o = ((size_t)hh*DD + row)*NN + n0 + half*16;
  *(s16x8*)(hthi + o)     = *(const s16x8*)&tH[row][half*16];
  *(s16x8*)(hthi + o + 8) = *(const s16x8*)&tH[row][half*16+8];
}

// ---- K3: fused 2-sweep att+hp. hi-only staging, depth-2 prefetch, uniform vmcnt(7)
//          -> store slack 2 chunks; stage(c) is in-order position 8 at each barrier.
__global__ __launch_bounds__(512, 8) void k_att(const u64* __restrict__ padj,
    const float* __restrict__ src, const float* __restrict__ dst,
    const short* __restrict__ hthi, float* __restrict__ dout){
  __shared__ short hA[64][CH2], hB[64][CH2];   // 8KB each
  __shared__ short pA[32][CH2], pB[32][CH2];   // 4KB each
  const size_t OUTOFF = (size_t)NN*HH*DD;
  int bid = blockIdx.x;
  int h = bid & 7, n0 = (bid >> 3) * 32;
  int t = threadIdx.x;
  int r = t>>4, j = t&15;
  int nrow = n0 + r;
  float srcv = src[h*NN + nrow];
  const float* dsth = dst + h*NN;
  const u64* arow = padj + (size_t)nrow*(NN/64);

  int wv = t>>6, lane = t&63, r15 = lane&15, g = lane>>4;
  int cblk = wv&3, nh = wv>>2;
  int drow = t>>3;
  int sslot = (t&7) ^ (drow&7);
  const short* gh = hthi + ((size_t)(h*DD) + drow)*NN + sslot*8;

  // stage chunk 0 early; sweep A's in-order consumed loads retire it before sweep B
  gload16(gh, &hA[wv*8][0]);

  // ---- sweep A: row sums (packed adj + broadcast dst), 128-wide chunks ----
  float psum = 0.f;
  for (int c=0;c<24;c++){
    u64 w0 = arow[c*2], w1 = arow[c*2+1];
    const float* dp = dsth + c*128 + j*4;
    float4 d0 = *(const float4*)dp, d1 = *(const float4*)(dp+64);
    float dj[8] = {d0.x,d0.y,d0.z,d0.w,d1.x,d1.y,d1.z,d1.w};
    #pragma unroll
    for (int e=0;e<8;e++){
      float ev = srcv + dj[e];
      ev = fmaxf(ev, SLOPEV*ev);
      u64 bits = (e<4) ? w0 : w1;
      float p = ((bits >> (j*4 + (e&3))) & 1ull) ? __expf(ev) : 0.f;
      psum += p;
    }
  }
  #pragma unroll
  for (int m=1;m<16;m<<=1) psum += __shfl_xor(psum, m, 64);
  float inv = (psum > 0.f) ? 1.f/psum : (1.f/(float)NN);
  bool am = !(psum > 0.f);

  // ---- sweep B: uniform pipelined loop, depth-2 bits/dv prefetch ----
  f32x4 acc = {0.f,0.f,0.f,0.f};
  float* attrow = dout + OUTOFF + ((size_t)(h*NN + nrow))*NN;
  int aoff0 = (cblk*16 + r15)*(CH2*2);
  int boff0 = (nh*16 + r15)*(CH2*2);
  int csw   = (r15&7)<<4;
  int pofs  = r*(CH2*2) + ((j*8) ^ ((r&7)<<4));

  const float* dvp = dsth + j*4;
  u64 bits  = arow[0];
  float4 dv  = *(const float4*)dvp;
  u64 bits1 = arow[1];
  float4 dv1 = *(const float4*)(dvp + CH2);

  #pragma unroll 2
  for (int c=0;c<NC2;c++){
    short (*hc)[CH2] = (c&1)?hB:hA;
    short (*hn)[CH2] = (c&1)?hA:hB;
    short (*pc)[CH2] = (c&1)?pB:pA;

    // vmem op 1: stage chunk c+1 (clamped; c=47 restages 47 into dead buffer)
    int cs = (c+1 < NC2) ? c+1 : NC2-1;
    gload16(gh + cs*CH2, &hn[wv*8][0]);
    // vmem ops 2,3: depth-2 prefetch (clamped index keeps count uniform)
    int cp = (c+2 < NC2) ? c+2 : NC2-1;
    u64 bits2 = arow[cp];
    float4 dv2 = *(const float4*)(dvp + cp*CH2);
    // compute p(c); vmem op 4: att nt-store; p -> LDS
    float o[4];
    #pragma unroll
    for (int e=0;e<4;e++){
      float ev = srcv + ((const float*)&dv)[e];
      ev = fmaxf(ev, SLOPEV*ev);
      float p = ((bits >> (j*4 + e)) & 1ull) ? __expf(ev) : 0.f;
      if (am) p = 1.f;
      o[e] = p * inv;
    }
    f32x4 s0 = {o[0],o[1],o[2],o[3]};
    __builtin_nontemporal_store(s0, (f32x4*)(attrow + c*CH2 + j*4));
    bf16x4 pb;
    #pragma unroll
    for (int e=0;e<4;e++) pb[e] = (__bf16)o[e];
    *(bf16x4*)((char*)pc + pofs) = pb;

    // barrier 1: vmcnt(7) -> stage(c) (position 8) forced; stores c, c-1 in flight
    __builtin_amdgcn_sched_barrier(0);
    asm volatile("s_waitcnt vmcnt(7) lgkmcnt(0)" ::: "memory");
    __builtin_amdgcn_sched_barrier(0);
    __builtin_amdgcn_s_barrier();
    __builtin_amdgcn_sched_barrier(0);

    // MFMA chunk c (hi only)
    const char* hcB = (const char*)hc;
    const char* pcB = (const char*)pc;
    #pragma unroll
    for (int ks=0;ks<2;ks++){
      int kb = (g*16 + ks*64) ^ csw;
      bf16x8 bf = *(const bf16x8*)(pcB + boff0 + kb);
      bf16x8 ah = *(const bf16x8*)(hcB + aoff0 + kb);
      acc = MFMA16(ah, bf, acc);
    }
    // barrier 2 (bare): protect hc/pc from next iteration's overwrite
    asm volatile("" ::: "memory");
    __builtin_amdgcn_s_barrier();
    __builtin_amdgcn_sched_barrier(0);

    bits = bits1; bits1 = bits2;
    dv = dv1; dv1 = dv2;
  }

  // ---- epilogue ----
  int n = n0 + nh*16 + r15;
  size_t ob = (size_t)n*(HH*DD) + h*DD + cblk*16 + g*4;
  __builtin_nontemporal_store(acc, (f32x4*)(dout+ob));
}

extern "C" void kernel_launch(void* const* d_in, const int* in_sizes, int n_in,
                              void* d_out, int out_size, void* d_ws, size_t ws_size,
                              hipStream_t stream) {
  const float* h   = (const float*)d_in[0];
  const int*   adj = (const int*)d_in[1];
  const float* W   = (const float*)d_in[2];
  const float* a   = (const float*)d_in[3];
  float* out = (float*)d_out;

  short* wthi = (short*)d_ws;
  short* wtlo = wthi + (size_t)HH*DD*FF;
  short* hthi = wtlo + (size_t)HH*DD*FF;
  float* wasrc= (float*)(hthi + (size_t)HH*DD*NN);
  float* wadst= wasrc + HH*FF;
  float* srcb = wadst + HH*FF;
  float* dstb = srcb + HH*NN;
  u64*   padj = (u64*)(dstb + HH*NN);

  k_wt    <<<dim3(FF/8, HH), 64, 0, stream>>>(W, a, wthi, wtlo, wasrc, wadst);
  k_pack  <<<dim3(2048), 256, 0, stream>>>(adj, padj);
  k_srcdst<<<dim3(NN/4), 256, 0, stream>>>(h, wasrc, wadst, srcb, dstb);
  k_ht    <<<dim3(NN/32, HH), 128, 0, stream>>>(h, wthi, wtlo, hthi);
  k_att   <<<dim3(NN/32*HH), 512, 0, stream>>>(padj, srcb, dstb, hthi, out);
}